// Round 4
// baseline (2888.622 us; speedup 1.0000x reference)
//
#include <hip/hip_runtime.h>
#include <math.h>

// Problem constants (from reference)
#define NG   1024        // graphs
#define NP   256         // nodes per graph
#define EPG  4096        // edges per graph
#define ETOT 4194304     // total edges
#define NTOT (NG * NP)   // 262144 nodes
#define FIN  7
#define HD   64
#define KC   50
#define SST  52          // padded row stride for S / AS rows
#define APS  53          // Apb stride (gcd(53,32)=1 -> ~2-way max on atomic merge)
#define CHK  64          // rows per K2 chunk
#define NCH  4           // chunks per graph

// NOTE (R2 post-mortem): __launch_bounds__ 2nd arg is CUDA-style min BLOCKS
// per CU. Keep caps such that VGPR budget >= 128 for weight-in-register GEMMs.
// NOTE (R3 post-mortem): LDS atomic scatter chains were k3's 1215 us. Gather
// via counting sort (built in k1) + bf16 S (2 blocks/CU) replaces it.

// Inter-kernel intermediates as statics: no hipMalloc, graph-capture safe.
// Every element is rewritten each launch before being read.
__device__ float g_xagg[NTOT * 8];                  // x+agg, padded to 8
__device__ unsigned short g_Sb[NTOT * SST];         // S rows, bf16, stride 52
__device__ unsigned char g_sdi[ETOT];               // di list, sorted by si
__device__ unsigned int g_roff[NG * 256];           // exclusive row offsets
__device__ float g_PTp[NG * NCH * HD * KC];         // xp partials [d][k]
__device__ float g_Gp[NG * NCH * KC * KC];          // G partials [k][c]
__device__ float g_Ap[NG * KC * KC];                // Ap [k][c]

__device__ __forceinline__ float bf2f(unsigned short u) {
    return __uint_as_float(((unsigned int)u) << 16);
}
__device__ __forceinline__ unsigned short f2bf(float f) {
    unsigned int x = __float_as_uint(f);
    return (unsigned short)((x + 0x7fffu + ((x >> 16) & 1u)) >> 16);   // RNE
}

__global__ void zero_ws(float* ws) {
    if (threadIdx.x < 4) ws[threadIdx.x] = 0.f;
}

// ws[0]=sumA2, ws[1]=sum S logS, ws[2]=sum AS.S, ws[3]=||G||^2
__global__ void finalize_k(const float* __restrict__ ws, float* __restrict__ out) {
    if (threadIdx.x == 0) {
        float num = ws[0] - 2.f * ws[2] + ws[3];
        float link = sqrtf(fmaxf(num, 0.f)) / 67108864.0f;   // / (B*n*n)
        float ent  = -ws[1] / 262144.0f;                     // / N
        out[2048] = link + ent;
    }
}

// generic block reduction; result valid on thread 0 only
__device__ __forceinline__ float blockReduceN(float v, float* red, int nw) {
    __syncthreads();   // protect red from previous use
    #pragma unroll
    for (int o = 32; o > 0; o >>= 1) v += __shfl_down(v, o);
    if ((threadIdx.x & 63) == 0) red[threadIdx.x >> 6] = v;
    __syncthreads();
    float r = 0.f;
    if (threadIdx.x == 0) {
        for (int i = 0; i < nw; ++i) r += red[i];
    }
    return r;
}

// ---- K1: edges -> cells, sum(A^2), si-counting-sort, GIN aggregation --------
// LDS ~61 KB -> 2 blocks/CU
__launch_bounds__(512, 2)
__global__ void k1_edges(const int* __restrict__ esrc, const int* __restrict__ edst,
                         const float* __restrict__ x, float* __restrict__ ws)
{
    __shared__ unsigned int cnt[8192];          // 32 KB (two u16 counters / word)
    __shared__ unsigned short cells[EPG];       // 8 KB
    __shared__ unsigned char sdi[EPG];          // 4 KB
    __shared__ unsigned int hist[256], roff[256], cursor[256];
    __shared__ float xt[NP * FIN];              // 7 KB
    __shared__ float agg[NP * FIN];             // 7 KB
    __shared__ float red[8];

    const int g = blockIdx.x, tid = threadIdx.x;
    const int lane = tid & 63, wid = tid >> 6;

    for (int e = tid; e < EPG; e += 512) {
        int s = esrc[g * EPG + e] & (NP - 1);
        int d = edst[g * EPG + e] & (NP - 1);
        cells[e] = (unsigned short)((s << 8) | d);
    }
    for (int i = tid; i < NP * FIN; i += 512) {
        xt[i]  = x[g * NP * FIN + i];
        agg[i] = 0.f;
    }
    if (tid < 256) hist[tid] = 0u;
    __syncthreads();

    // sum(A^2): 4 chunks of 16384 cells, two u16 counters per u32 word;
    // also si histogram (once)
    float sumA2 = 0.f;
    for (int ch = 0; ch < 4; ++ch) {
        for (int i = tid; i < 8192; i += 512) cnt[i] = 0u;
        __syncthreads();
        int base = ch << 14;
        for (int e = tid; e < EPG; e += 512) {
            int c = cells[e];
            int r = c - base;
            if ((unsigned)r < 16384u)
                atomicAdd(&cnt[r >> 1], (r & 1) ? 0x10000u : 1u);
            if (ch == 0) atomicAdd(&hist[c >> 8], 1u);
        }
        __syncthreads();
        for (int i = tid; i < 8192; i += 512) {
            unsigned v = cnt[i];
            float m0 = (float)(v & 0xffffu), m1 = (float)(v >> 16);
            sumA2 += m0 * m0 + m1 * m1;
        }
        __syncthreads();
    }

    // exclusive prefix scan of hist (wave 0), fill roff + cursor
    if (wid == 0) {
        unsigned carry = 0;
        for (int c = 0; c < 4; ++c) {
            unsigned v = hist[c * 64 + lane];
            unsigned s = v;
            #pragma unroll
            for (int o = 1; o < 64; o <<= 1) {
                unsigned t = __shfl_up(s, o);
                if (lane >= o) s += t;
            }
            unsigned excl = s - v + carry;
            roff[c * 64 + lane] = excl;
            cursor[c * 64 + lane] = excl;
            carry += __shfl(s, 63);
        }
    }
    __syncthreads();

    // place: si-sorted di list
    for (int e = tid; e < EPG; e += 512) {
        int c = cells[e];
        unsigned pos = atomicAdd(&cursor[c >> 8], 1u);
        sdi[pos] = (unsigned char)(c & 255);
    }

    // GIN aggregation: agg[di] += x[si]
    for (int e = tid; e < EPG; e += 512) {
        int c = cells[e]; int si = c >> 8, di = c & 255;
        #pragma unroll
        for (int f = 0; f < FIN; ++f)
            atomicAdd(&agg[di * FIN + f], xt[si * FIN + f]);
    }
    __syncthreads();

    // write x+agg (padded to 8), sorted list, offsets
    for (int i = tid; i < NP * 8; i += 512) {
        int n = i >> 3, f = i & 7;
        float v = (f < FIN) ? (xt[n * FIN + f] + agg[n * FIN + f]) : 0.f;
        g_xagg[g * NP * 8 + i] = v;
    }
    for (int i = tid; i < EPG / 4; i += 512)
        ((unsigned int*)g_sdi)[g * (EPG / 4) + i] = ((const unsigned int*)sdi)[i];
    if (tid < 256) g_roff[g * 256 + tid] = roff[tid];

    float r = blockReduceN(sumA2, red, 8);
    if (tid == 0) atomicAdd(&ws[0], r);
}

// ---------------- K2: MLP1 + softmax S + xp/G partials (64-row chunks) --------
// LDS ~54.4 KB -> 2 blocks/CU
__launch_bounds__(512, 2)
__global__ void k2_mlp(const float* __restrict__ W1a, const float* __restrict__ b1a,
                       const float* __restrict__ W1b, const float* __restrict__ b1b,
                       const float* __restrict__ Wp,  const float* __restrict__ bp,
                       float* __restrict__ ws)
{
    __shared__ __align__(16) float xt[CHK * 8];        // 2 KB
    __shared__ __align__(16) float hrow[CHK * HD];     // 16 KB (t1 then h in-place)
    __shared__ __align__(16) float St[CHK * SST];      // 13.3 KB
    __shared__ __align__(16) float PT[HD * KC];        // 12.8 KB
    __shared__ __align__(16) float Gb[KC * KC];        // 10 KB
    __shared__ float red[8];

    const int b = blockIdx.x;
    const int rbase = b * CHK;                   // global row base (g*256 + c*64)
    const int tid = threadIdx.x;
    const int lane = tid & 63, wid = tid >> 6;
    const int kk = (lane < KC) ? lane : (KC - 1);

    float entL = 0.f;

    xt[tid] = g_xagg[rbase * 8 + tid];           // 512 = CHK*8 exactly
    for (int i = tid; i < HD * KC; i += 512) PT[i] = 0.f;
    for (int i = tid; i < KC * KC; i += 512) Gb[i] = 0.f;
    __syncthreads();

    // t1 = relu((x+agg) @ W1a + b1a)
    {
        float w1r[FIN];
        #pragma unroll
        for (int f = 0; f < FIN; ++f) w1r[f] = W1a[f * HD + lane];
        float br = b1a[lane];
        for (int n = wid; n < CHK; n += 8) {
            float a = br;
            #pragma unroll
            for (int f = 0; f < FIN; ++f) a += xt[n * 8 + f] * w1r[f];
            hrow[n * HD + lane] = fmaxf(a, 0.f);
        }
    }
    __syncthreads();

    // h = t1 @ W1b + b1b (rows private to a wave; in-place)
    {
        float wr[HD];
        #pragma unroll
        for (int j = 0; j < HD; ++j) wr[j] = W1b[j * HD + lane];
        float br = b1b[lane];
        for (int n = wid; n < CHK; n += 8) {
            float a0 = br, a1 = 0.f, a2 = 0.f, a3 = 0.f;
            const float4* t4 = (const float4*)&hrow[n * HD];
            #pragma unroll
            for (int i = 0; i < 16; ++i) {
                float4 v = t4[i];
                a0 += v.x * wr[4*i]; a1 += v.y * wr[4*i+1];
                a2 += v.z * wr[4*i+2]; a3 += v.w * wr[4*i+3];
            }
            hrow[n * HD + lane] = (a0 + a1) + (a2 + a3);
        }
    }
    __syncthreads();

    // S = softmax(h @ Wp + bp); entropy partial
    {
        float wr[HD];
        #pragma unroll
        for (int j = 0; j < HD; ++j) wr[j] = Wp[j * KC + kk];
        float br = bp[kk];
        for (int n = wid; n < CHK; n += 8) {
            float a0 = br, a1 = 0.f, a2 = 0.f, a3 = 0.f;
            const float4* h4 = (const float4*)&hrow[n * HD];
            #pragma unroll
            for (int i = 0; i < 16; ++i) {
                float4 v = h4[i];
                a0 += v.x * wr[4*i]; a1 += v.y * wr[4*i+1];
                a2 += v.z * wr[4*i+2]; a3 += v.w * wr[4*i+3];
            }
            float a = (a0 + a1) + (a2 + a3);
            if (lane >= KC) a = -INFINITY;
            float m = a;
            #pragma unroll
            for (int o = 32; o > 0; o >>= 1) m = fmaxf(m, __shfl_xor(m, o));
            float e = expf(a - m);
            float ss = e;
            #pragma unroll
            for (int o = 32; o > 0; o >>= 1) ss += __shfl_xor(ss, o);
            float s = e / ss;
            if (lane < SST) St[n * SST + lane] = s;    // pads (50,51) = 0
            if (lane < KC) entL += s * logf(s + 1e-15f);
        }
    }
    __syncthreads();

    // persist S rows as bf16 pairs (coalesced u32)
    for (int i = tid; i < CHK * SST / 2; i += 512) {
        float a = St[2 * i], bb = St[2 * i + 1];
        ((unsigned int*)g_Sb)[rbase * (SST / 2) + i] =
            (unsigned int)f2bf(a) | ((unsigned int)f2bf(bb) << 16);
    }

    // xp partial (waves 0-3) and G partial (waves 4-7)
    if (wid < 4) {
        float acc[HD];
        #pragma unroll
        for (int c = 0; c < HD; ++c) acc[c] = 0.f;
        int n0 = wid * 16;
        for (int n = n0; n < n0 + 16; ++n) {
            float sk = St[n * SST + kk];
            const float4* h4 = (const float4*)&hrow[n * HD];
            #pragma unroll
            for (int i = 0; i < 16; ++i) {
                float4 v = h4[i];
                acc[4*i]   += sk * v.x; acc[4*i+1] += sk * v.y;
                acc[4*i+2] += sk * v.z; acc[4*i+3] += sk * v.w;
            }
        }
        if (lane < KC) {
            #pragma unroll
            for (int c = 0; c < HD; ++c) atomicAdd(&PT[c * KC + lane], acc[c]);
        }
    } else {
        float acc[SST];
        #pragma unroll
        for (int c = 0; c < SST; ++c) acc[c] = 0.f;
        int n0 = (wid - 4) * 16;
        for (int n = n0; n < n0 + 16; ++n) {
            float sk = St[n * SST + kk];
            const float4* s4 = (const float4*)&St[n * SST];
            #pragma unroll
            for (int i = 0; i < 13; ++i) {
                float4 v = s4[i];
                acc[4*i]   += sk * v.x; acc[4*i+1] += sk * v.y;
                acc[4*i+2] += sk * v.z; acc[4*i+3] += sk * v.w;
            }
        }
        if (lane < KC) {
            #pragma unroll
            for (int c = 0; c < KC; ++c) atomicAdd(&Gb[lane * KC + c], acc[c]);
        }
    }
    __syncthreads();

    // write partial slots (indexed by blockIdx = g*4+c)
    for (int i = tid; i < HD * KC; i += 512) g_PTp[b * HD * KC + i] = PT[i];
    for (int i = tid; i < KC * KC; i += 512) g_Gp[b * KC * KC + i] = Gb[i];

    float r = blockReduceN(entL, red, 8);
    if (tid == 0) atomicAdd(&ws[1], r);
}

// ---- K3: AS by sorted gather (no atomics) + Ap = S^T AS + sum(AS.S) ---------
// LDS ~69 KB -> 2 blocks/CU
__launch_bounds__(512, 2)
__global__ void k3_as(float* __restrict__ ws)
{
    __shared__ __align__(16) unsigned short Stb[NP * SST];  // 26.6 KB (bf16 S)
    __shared__ __align__(16) float ASh[128 * SST];          // 26.6 KB (half-graph AS)
    __shared__ __align__(16) float Apb[KC * APS];           // 10.6 KB
    __shared__ __align__(16) unsigned char sdi[EPG];        // 4 KB
    __shared__ unsigned int roff[256];                      // 1 KB
    __shared__ float red[8];

    const int g = blockIdx.x, tid = threadIdx.x;
    const int lane = tid & 63, wid = tid >> 6;
    const int kk = (lane < KC) ? lane : (KC - 1);

    for (int i = tid; i < NP * SST / 2; i += 512)
        ((unsigned int*)Stb)[i] = ((const unsigned int*)g_Sb)[g * NP * (SST / 2) + i];
    for (int i = tid; i < EPG / 4; i += 512)
        ((unsigned int*)sdi)[i] = ((const unsigned int*)g_sdi)[g * (EPG / 4) + i];
    if (tid < 256) roff[tid] = g_roff[g * 256 + tid];
    for (int i = tid; i < KC * APS; i += 512) Apb[i] = 0.f;
    __syncthreads();

    float ap[SST];
    #pragma unroll
    for (int c = 0; c < SST; ++c) ap[c] = 0.f;
    float sumASSt = 0.f;

    for (int half = 0; half < 2; ++half) {
        // gather AS rows: AS[row,c] = sum_{e in row} S[di_e, c]
        for (int r = wid * 16; r < wid * 16 + 16; ++r) {
            int row = half * 128 + r;
            int beg = roff[row];
            int end = (row == 255) ? EPG : roff[row + 1];
            float acc = 0.f;
            for (int e = beg; e < end; ++e) {
                int di = sdi[e];
                acc += bf2f(Stb[di * SST + kk]);
            }
            if (lane < SST) ASh[r * SST + lane] = (lane < KC) ? acc : 0.f;
        }
        __syncthreads();

        // ap[c] += S[row,kk] * AS[row,c]; sumASSt += S[row,kk]*AS[row,kk]
        for (int r = wid * 16; r < wid * 16 + 16; ++r) {
            int row = half * 128 + r;
            float sk = bf2f(Stb[row * SST + kk]);
            if (lane < KC) sumASSt += sk * ASh[r * SST + kk];
            const float4* a4 = (const float4*)&ASh[r * SST];
            #pragma unroll
            for (int i = 0; i < 13; ++i) {
                float4 v = a4[i];
                ap[4*i]   += sk * v.x; ap[4*i+1] += sk * v.y;
                ap[4*i+2] += sk * v.z; ap[4*i+3] += sk * v.w;
            }
        }
        __syncthreads();    // before next half overwrites ASh
    }

    if (lane < KC) {
        #pragma unroll
        for (int c = 0; c < KC; ++c) atomicAdd(&Apb[kk * APS + c], ap[c]);
    }
    __syncthreads();

    for (int i = tid; i < KC * KC; i += 512) {
        int k = i / KC, c = i - k * KC;
        g_Ap[g * KC * KC + i] = Apb[k * APS + c];
    }

    float r = blockReduceN(sumASSt, red, 8);
    if (tid == 0) atomicAdd(&ws[2], r);
}

// ---------------- K4: combine partials, ||G||^2, dense GIN, classifier -------
// LDS ~48.4 KB -> 3 blocks/CU
__launch_bounds__(256, 3)
__global__ void k4_head(const float* __restrict__ W2a, const float* __restrict__ b2a,
                        const float* __restrict__ W2b, const float* __restrict__ b2b,
                        const float* __restrict__ Wl,  const float* __restrict__ bl,
                        float* __restrict__ out, float* __restrict__ ws)
{
    __shared__ __align__(16) float PT[HD * KC];     // 12.8 KB
    __shared__ __align__(16) float Ap[KC * KC];     // 10 KB
    __shared__ __align__(16) float h2[KC * HD];     // 12.8 KB
    __shared__ __align__(16) float tt[KC * HD];     // 12.8 KB
    __shared__ float red[4];

    const int g = blockIdx.x, tid = threadIdx.x;
    const int lane = tid & 63, wid = tid >> 6;

    // sum xp partials
    for (int i = tid; i < HD * KC; i += 256) {
        float v = 0.f;
        #pragma unroll
        for (int c = 0; c < NCH; ++c) v += g_PTp[(g * NCH + c) * HD * KC + i];
        PT[i] = v;
    }
    // ||G||^2 partial (sum chunk partials first, then square)
    float sumG2 = 0.f;
    for (int i = tid; i < KC * KC; i += 256) {
        float v = 0.f;
        #pragma unroll
        for (int c = 0; c < NCH; ++c) v += g_Gp[(g * NCH + c) * KC * KC + i];
        sumG2 += v * v;
        Ap[i] = g_Ap[g * KC * KC + i];
    }
    __syncthreads();

    // h2 = xp + Ap @ xp   (PT[d][k] = xp[k][d])
    for (int k = wid; k < KC; k += 4) {
        float a = PT[lane * KC + k];
        #pragma unroll
        for (int l = 0; l < KC; ++l)
            a += Ap[k * KC + l] * PT[lane * KC + l];
        h2[k * HD + lane] = a;
    }
    __syncthreads();

    // t = relu(h2 @ W2a + b2a)
    {
        float wr[HD];
        #pragma unroll
        for (int d = 0; d < HD; ++d) wr[d] = W2a[d * HD + lane];
        float br = b2a[lane];
        for (int k = wid; k < KC; k += 4) {
            float a0 = br, a1 = 0.f, a2 = 0.f, a3 = 0.f;
            const float4* h4 = (const float4*)&h2[k * HD];
            #pragma unroll
            for (int i = 0; i < 16; ++i) {
                float4 v = h4[i];
                a0 += v.x * wr[4*i]; a1 += v.y * wr[4*i+1];
                a2 += v.z * wr[4*i+2]; a3 += v.w * wr[4*i+3];
            }
            tt[k * HD + lane] = fmaxf((a0 + a1) + (a2 + a3), 0.f);
        }
    }
    __syncthreads();

    // h3 = t @ W2b + b2b; fold mean over k and Wl into logits partials
    float l0 = 0.f, l1 = 0.f;
    {
        float wr[HD];
        #pragma unroll
        for (int j = 0; j < HD; ++j) wr[j] = W2b[j * HD + lane];
        float br = b2b[lane];
        float wl0 = Wl[lane * 2], wl1 = Wl[lane * 2 + 1];
        for (int k = wid; k < KC; k += 4) {
            float a0 = br, a1 = 0.f, a2 = 0.f, a3 = 0.f;
            const float4* t4 = (const float4*)&tt[k * HD];
            #pragma unroll
            for (int i = 0; i < 16; ++i) {
                float4 v = t4[i];
                a0 += v.x * wr[4*i]; a1 += v.y * wr[4*i+1];
                a2 += v.z * wr[4*i+2]; a3 += v.w * wr[4*i+3];
            }
            float a = (a0 + a1) + (a2 + a3);
            l0 += a * wl0; l1 += a * wl1;
        }
    }

    float rG2 = blockReduceN(sumG2, red, 4);
    float rl0 = blockReduceN(l0, red, 4);
    float rl1 = blockReduceN(l1, red, 4);
    if (tid == 0) {
        atomicAdd(&ws[3], rG2);
        float g0 = bl[0] + rl0 * (1.f / KC);
        float g1 = bl[1] + rl1 * (1.f / KC);
        float mm = fmaxf(g0, g1);
        float lse = mm + logf(expf(g0 - mm) + expf(g1 - mm));
        out[2 * g]     = g0 - lse;
        out[2 * g + 1] = g1 - lse;
    }
}

extern "C" void kernel_launch(void* const* d_in, const int* in_sizes, int n_in,
                              void* d_out, int out_size, void* d_ws, size_t ws_size,
                              hipStream_t stream) {
    const float* x    = (const float*)d_in[0];
    const float* W1a  = (const float*)d_in[1];
    const float* b1a  = (const float*)d_in[2];
    const float* W1b  = (const float*)d_in[3];
    const float* b1b  = (const float*)d_in[4];
    const float* Wp   = (const float*)d_in[5];
    const float* bp   = (const float*)d_in[6];
    const float* W2a  = (const float*)d_in[7];
    const float* b2a  = (const float*)d_in[8];
    const float* W2b  = (const float*)d_in[9];
    const float* b2b  = (const float*)d_in[10];
    const float* Wl   = (const float*)d_in[11];
    const float* bl   = (const float*)d_in[12];
    const int*   eidx = (const int*)d_in[13];   // [2, E] int32
    float* out = (float*)d_out;
    float* ws  = (float*)d_ws;

    zero_ws<<<1, 64, 0, stream>>>(ws);
    k1_edges<<<NG, 512, 0, stream>>>(eidx, eidx + ETOT, x, ws);
    k2_mlp<<<NG * NCH, 512, 0, stream>>>(W1a, b1a, W1b, b1b, Wp, bp, ws);
    k3_as<<<NG, 512, 0, stream>>>(ws);
    k4_head<<<NG, 256, 0, stream>>>(W2a, b2a, W2b, b2b, Wl, bl, out, ws);
    finalize_k<<<1, 64, 0, stream>>>(ws, out);
}

// Round 5
// 1305.292 us; speedup vs baseline: 2.2130x; 2.2130x over previous
//
#include <hip/hip_runtime.h>
#include <math.h>

// Problem constants (from reference)
#define NG   1024        // graphs
#define NP   256         // nodes per graph
#define EPG  4096        // edges per graph
#define ETOT 4194304     // total edges
#define NTOT (NG * NP)   // 262144 nodes
#define FIN  7
#define HD   64
#define KC   50
#define SST  52          // padded row stride for S inside k2 (16B-aligned rows)
#define SP   50          // packed row stride for g_S / k3
#define CHK  64          // rows per K2 chunk
#define NCH  4           // chunks per graph

// NOTE (R2 post-mortem): __launch_bounds__ 2nd arg is CUDA-style min BLOCKS
// per CU. Keep caps such that VGPR budget >= 128 for weight-in-register GEMMs.
// NOTE (R3 post-mortem): LDS atomic scatter chains cost 1215 us -> gather via
// counting sort (built in k1).
// NOTE (R4 post-mortem): persistent float ap[52] per-lane array spilled at the
// 128-VGPR cap -> 4.65 GB scratch traffic. k3 now accumulates Ap as <=7 scalar
// regs per wave (wave-row mapping) and uses trace(Ap) for sum(A.SSt).

// Inter-kernel intermediates as statics: no hipMalloc, graph-capture safe.
// Every element is rewritten each launch before being read.
__device__ float g_xagg[NTOT * 8];                  // x+agg, padded to 8
__device__ float g_S[NTOT * SP];                    // S rows, fp32, packed 50
__device__ unsigned char g_sdi[ETOT];               // di list, sorted by si
__device__ unsigned int g_roff[NG * 256];           // exclusive row offsets
__device__ float g_PTp[NG * NCH * HD * KC];         // xp partials [d][k]
__device__ float g_Gp[NG * NCH * KC * KC];          // G partials [k][c]
__device__ float g_Ap[NG * KC * KC];                // Ap [k][c]

__global__ void zero_ws(float* ws) {
    if (threadIdx.x < 4) ws[threadIdx.x] = 0.f;
}

// ws[0]=sumA2, ws[1]=sum S logS, ws[2]=trace(Ap)=sum(A.SSt), ws[3]=||G||^2
__global__ void finalize_k(const float* __restrict__ ws, float* __restrict__ out) {
    if (threadIdx.x == 0) {
        float num = ws[0] - 2.f * ws[2] + ws[3];
        float link = sqrtf(fmaxf(num, 0.f)) / 67108864.0f;   // / (B*n*n)
        float ent  = -ws[1] / 262144.0f;                     // / N
        out[2048] = link + ent;
    }
}

// generic block reduction; result valid on thread 0 only
__device__ __forceinline__ float blockReduceN(float v, float* red, int nw) {
    __syncthreads();   // protect red from previous use
    #pragma unroll
    for (int o = 32; o > 0; o >>= 1) v += __shfl_down(v, o);
    if ((threadIdx.x & 63) == 0) red[threadIdx.x >> 6] = v;
    __syncthreads();
    float r = 0.f;
    if (threadIdx.x == 0) {
        for (int i = 0; i < nw; ++i) r += red[i];
    }
    return r;
}

// ---- K1: edges -> cells, sum(A^2), si-counting-sort, GIN aggregation --------
// LDS ~61 KB -> 2 blocks/CU
__launch_bounds__(512, 2)
__global__ void k1_edges(const int* __restrict__ esrc, const int* __restrict__ edst,
                         const float* __restrict__ x, float* __restrict__ ws)
{
    __shared__ unsigned int cnt[8192];          // 32 KB (two u16 counters / word)
    __shared__ unsigned short cells[EPG];       // 8 KB
    __shared__ unsigned char sdi[EPG];          // 4 KB
    __shared__ unsigned int hist[256], roff[256], cursor[256];
    __shared__ float xt[NP * FIN];              // 7 KB
    __shared__ float agg[NP * FIN];             // 7 KB
    __shared__ float red[8];

    const int g = blockIdx.x, tid = threadIdx.x;
    const int lane = tid & 63, wid = tid >> 6;

    for (int e = tid; e < EPG; e += 512) {
        int s = esrc[g * EPG + e] & (NP - 1);
        int d = edst[g * EPG + e] & (NP - 1);
        cells[e] = (unsigned short)((s << 8) | d);
    }
    for (int i = tid; i < NP * FIN; i += 512) {
        xt[i]  = x[g * NP * FIN + i];
        agg[i] = 0.f;
    }
    if (tid < 256) hist[tid] = 0u;
    __syncthreads();

    // sum(A^2): 4 chunks of 16384 cells, two u16 counters per u32 word;
    // also si histogram (once)
    float sumA2 = 0.f;
    for (int ch = 0; ch < 4; ++ch) {
        for (int i = tid; i < 8192; i += 512) cnt[i] = 0u;
        __syncthreads();
        int base = ch << 14;
        for (int e = tid; e < EPG; e += 512) {
            int c = cells[e];
            int r = c - base;
            if ((unsigned)r < 16384u)
                atomicAdd(&cnt[r >> 1], (r & 1) ? 0x10000u : 1u);
            if (ch == 0) atomicAdd(&hist[c >> 8], 1u);
        }
        __syncthreads();
        for (int i = tid; i < 8192; i += 512) {
            unsigned v = cnt[i];
            float m0 = (float)(v & 0xffffu), m1 = (float)(v >> 16);
            sumA2 += m0 * m0 + m1 * m1;
        }
        __syncthreads();
    }

    // exclusive prefix scan of hist (wave 0), fill roff + cursor
    if (wid == 0) {
        unsigned carry = 0;
        for (int c = 0; c < 4; ++c) {
            unsigned v = hist[c * 64 + lane];
            unsigned s = v;
            #pragma unroll
            for (int o = 1; o < 64; o <<= 1) {
                unsigned t = __shfl_up(s, o);
                if (lane >= o) s += t;
            }
            unsigned excl = s - v + carry;
            roff[c * 64 + lane] = excl;
            cursor[c * 64 + lane] = excl;
            carry += __shfl(s, 63);
        }
    }
    __syncthreads();

    // place: si-sorted di list
    for (int e = tid; e < EPG; e += 512) {
        int c = cells[e];
        unsigned pos = atomicAdd(&cursor[c >> 8], 1u);
        sdi[pos] = (unsigned char)(c & 255);
    }

    // GIN aggregation: agg[di] += x[si]
    for (int e = tid; e < EPG; e += 512) {
        int c = cells[e]; int si = c >> 8, di = c & 255;
        #pragma unroll
        for (int f = 0; f < FIN; ++f)
            atomicAdd(&agg[di * FIN + f], xt[si * FIN + f]);
    }
    __syncthreads();

    // write x+agg (padded to 8), sorted list, offsets
    for (int i = tid; i < NP * 8; i += 512) {
        int n = i >> 3, f = i & 7;
        float v = (f < FIN) ? (xt[n * FIN + f] + agg[n * FIN + f]) : 0.f;
        g_xagg[g * NP * 8 + i] = v;
    }
    for (int i = tid; i < EPG / 4; i += 512)
        ((unsigned int*)g_sdi)[g * (EPG / 4) + i] = ((const unsigned int*)sdi)[i];
    if (tid < 256) g_roff[g * 256 + tid] = roff[tid];

    float r = blockReduceN(sumA2, red, 8);
    if (tid == 0) atomicAdd(&ws[0], r);
}

// ---------------- K2: MLP1 + softmax S + xp/G partials (64-row chunks) --------
// LDS ~54.4 KB -> 2 blocks/CU
__launch_bounds__(512, 2)
__global__ void k2_mlp(const float* __restrict__ W1a, const float* __restrict__ b1a,
                       const float* __restrict__ W1b, const float* __restrict__ b1b,
                       const float* __restrict__ Wp,  const float* __restrict__ bp,
                       float* __restrict__ ws)
{
    __shared__ __align__(16) float xt[CHK * 8];        // 2 KB
    __shared__ __align__(16) float hrow[CHK * HD];     // 16 KB (t1 then h in-place)
    __shared__ __align__(16) float St[CHK * SST];      // 13.3 KB
    __shared__ __align__(16) float PT[HD * KC];        // 12.8 KB
    __shared__ __align__(16) float Gb[KC * KC];        // 10 KB
    __shared__ float red[8];

    const int b = blockIdx.x;
    const int rbase = b * CHK;                   // global row base (g*256 + c*64)
    const int tid = threadIdx.x;
    const int lane = tid & 63, wid = tid >> 6;
    const int kk = (lane < KC) ? lane : (KC - 1);

    float entL = 0.f;

    xt[tid] = g_xagg[rbase * 8 + tid];           // 512 = CHK*8 exactly
    for (int i = tid; i < HD * KC; i += 512) PT[i] = 0.f;
    for (int i = tid; i < KC * KC; i += 512) Gb[i] = 0.f;
    __syncthreads();

    // t1 = relu((x+agg) @ W1a + b1a)
    {
        float w1r[FIN];
        #pragma unroll
        for (int f = 0; f < FIN; ++f) w1r[f] = W1a[f * HD + lane];
        float br = b1a[lane];
        for (int n = wid; n < CHK; n += 8) {
            float a = br;
            #pragma unroll
            for (int f = 0; f < FIN; ++f) a += xt[n * 8 + f] * w1r[f];
            hrow[n * HD + lane] = fmaxf(a, 0.f);
        }
    }
    __syncthreads();

    // h = t1 @ W1b + b1b (rows private to a wave; in-place)
    {
        float wr[HD];
        #pragma unroll
        for (int j = 0; j < HD; ++j) wr[j] = W1b[j * HD + lane];
        float br = b1b[lane];
        for (int n = wid; n < CHK; n += 8) {
            float a0 = br, a1 = 0.f, a2 = 0.f, a3 = 0.f;
            const float4* t4 = (const float4*)&hrow[n * HD];
            #pragma unroll
            for (int i = 0; i < 16; ++i) {
                float4 v = t4[i];
                a0 += v.x * wr[4*i]; a1 += v.y * wr[4*i+1];
                a2 += v.z * wr[4*i+2]; a3 += v.w * wr[4*i+3];
            }
            hrow[n * HD + lane] = (a0 + a1) + (a2 + a3);
        }
    }
    __syncthreads();

    // S = softmax(h @ Wp + bp); entropy partial
    {
        float wr[HD];
        #pragma unroll
        for (int j = 0; j < HD; ++j) wr[j] = Wp[j * KC + kk];
        float br = bp[kk];
        for (int n = wid; n < CHK; n += 8) {
            float a0 = br, a1 = 0.f, a2 = 0.f, a3 = 0.f;
            const float4* h4 = (const float4*)&hrow[n * HD];
            #pragma unroll
            for (int i = 0; i < 16; ++i) {
                float4 v = h4[i];
                a0 += v.x * wr[4*i]; a1 += v.y * wr[4*i+1];
                a2 += v.z * wr[4*i+2]; a3 += v.w * wr[4*i+3];
            }
            float a = (a0 + a1) + (a2 + a3);
            if (lane >= KC) a = -INFINITY;
            float m = a;
            #pragma unroll
            for (int o = 32; o > 0; o >>= 1) m = fmaxf(m, __shfl_xor(m, o));
            float e = expf(a - m);
            float ss = e;
            #pragma unroll
            for (int o = 32; o > 0; o >>= 1) ss += __shfl_xor(ss, o);
            float s = e / ss;
            if (lane < SST) St[n * SST + lane] = s;    // pads (50,51) = 0
            if (lane < KC) entL += s * logf(s + 1e-15f);
        }
    }
    __syncthreads();

    // persist S rows fp32, packed stride 50 (coalesced)
    for (int i = tid; i < CHK * SP; i += 512) {
        int r = i / SP, cc = i - r * SP;
        g_S[(size_t)rbase * SP + i] = St[r * SST + cc];
    }

    // xp partial (waves 0-3) and G partial (waves 4-7)
    if (wid < 4) {
        float acc[HD];
        #pragma unroll
        for (int c = 0; c < HD; ++c) acc[c] = 0.f;
        int n0 = wid * 16;
        for (int n = n0; n < n0 + 16; ++n) {
            float sk = St[n * SST + kk];
            const float4* h4 = (const float4*)&hrow[n * HD];
            #pragma unroll
            for (int i = 0; i < 16; ++i) {
                float4 v = h4[i];
                acc[4*i]   += sk * v.x; acc[4*i+1] += sk * v.y;
                acc[4*i+2] += sk * v.z; acc[4*i+3] += sk * v.w;
            }
        }
        if (lane < KC) {
            #pragma unroll
            for (int c = 0; c < HD; ++c) atomicAdd(&PT[c * KC + lane], acc[c]);
        }
    } else {
        float acc[SST];
        #pragma unroll
        for (int c = 0; c < SST; ++c) acc[c] = 0.f;
        int n0 = (wid - 4) * 16;
        for (int n = n0; n < n0 + 16; ++n) {
            float sk = St[n * SST + kk];
            const float4* s4 = (const float4*)&St[n * SST];
            #pragma unroll
            for (int i = 0; i < 13; ++i) {
                float4 v = s4[i];
                acc[4*i]   += sk * v.x; acc[4*i+1] += sk * v.y;
                acc[4*i+2] += sk * v.z; acc[4*i+3] += sk * v.w;
            }
        }
        if (lane < KC) {
            #pragma unroll
            for (int c = 0; c < KC; ++c) atomicAdd(&Gb[lane * KC + c], acc[c]);
        }
    }
    __syncthreads();

    // write partial slots (indexed by blockIdx = g*4+c)
    for (int i = tid; i < HD * KC; i += 512) g_PTp[b * HD * KC + i] = PT[i];
    for (int i = tid; i < KC * KC; i += 512) g_Gp[b * KC * KC + i] = Gb[i];

    float r = blockReduceN(entL, red, 8);
    if (tid == 0) atomicAdd(&ws[1], r);
}

// ---- K3: AS by sorted gather (quarters) + wave-row Ap + trace(Ap) -----------
// LDS ~69 KB -> 2 blocks/CU. Persistent per-lane state: 7 scalar regs (no spill).
__launch_bounds__(512, 2)
__global__ void k3_as(float* __restrict__ ws)
{
    __shared__ __align__(16) float St[NP * SP];       // 50 KB, packed stride 50
    __shared__ __align__(16) float ASq[64 * SP];      // 12.5 KB (quarter of AS)
    __shared__ __align__(16) unsigned char sdi[EPG];  // 4 KB
    __shared__ unsigned int roff[NP + 1];             // 1 KB
    __shared__ float red[8];

    const int g = blockIdx.x, tid = threadIdx.x;
    const int lane = tid & 63, wid = tid >> 6;
    const int cc = (lane < SP) ? lane : (SP - 1);     // clamped column index

    // loads (St region is contiguous & 16B-aligned: 256*50*4 = 51200 B)
    for (int i = tid; i < NP * SP / 4; i += 512)
        ((float4*)St)[i] = ((const float4*)(g_S + (size_t)g * NP * SP))[i];
    for (int i = tid; i < EPG / 4; i += 512)
        ((unsigned int*)sdi)[i] = ((const unsigned int*)g_sdi)[g * (EPG / 4) + i];
    if (tid < NP) roff[tid] = g_roff[g * NP + tid];
    if (tid == NP) roff[NP] = EPG;
    __syncthreads();

    float ap[7];
    #pragma unroll
    for (int j = 0; j < 7; ++j) ap[j] = 0.f;

    for (int q = 0; q < 4; ++q) {
        // gather quarter of AS: AS[n,c] = sum_{e: si=n} S[di_e, c]
        for (int rr = wid * 8; rr < wid * 8 + 8; ++rr) {
            int n = q * 64 + rr;
            int beg = roff[n], end = roff[n + 1];
            float acc = 0.f;
            for (int e = beg; e < end; ++e)
                acc += St[sdi[e] * SP + cc];          // lane-consecutive, 2-way free
            if (lane < SP) ASq[rr * SP + lane] = acc;
        }
        __syncthreads();

        // Ap[k,c] += sum_n S[n,k] * AS[n,c]; wave w owns rows k = w + 8j
        for (int n = 0; n < 64; ++n) {
            float as = ASq[n * SP + cc];
            const float* sr = &St[(q * 64 + n) * SP];
            #pragma unroll
            for (int j = 0; j < 7; ++j) {
                int k = wid + j * 8;
                int kcl = (k < SP) ? k : (SP - 1);
                ap[j] += sr[kcl] * as;                // sr[kcl]: wave-uniform bcast
            }
        }
        __syncthreads();    // before next quarter overwrites ASq
    }

    // write Ap rows; trace accumulates sum(A .* SSt)
    float tr = 0.f;
    #pragma unroll
    for (int j = 0; j < 7; ++j) {
        int k = wid + j * 8;
        if (k < SP && lane < SP) {
            g_Ap[(size_t)g * SP * SP + k * SP + lane] = ap[j];
            if (lane == k) tr += ap[j];
        }
    }

    float r = blockReduceN(tr, red, 8);
    if (tid == 0) atomicAdd(&ws[2], r);
}

// ---------------- K4: combine partials, ||G||^2, dense GIN, classifier -------
// LDS ~48.4 KB -> 3 blocks/CU
__launch_bounds__(256, 3)
__global__ void k4_head(const float* __restrict__ W2a, const float* __restrict__ b2a,
                        const float* __restrict__ W2b, const float* __restrict__ b2b,
                        const float* __restrict__ Wl,  const float* __restrict__ bl,
                        float* __restrict__ out, float* __restrict__ ws)
{
    __shared__ __align__(16) float PT[HD * KC];     // 12.8 KB
    __shared__ __align__(16) float Ap[KC * KC];     // 10 KB
    __shared__ __align__(16) float h2[KC * HD];     // 12.8 KB
    __shared__ __align__(16) float tt[KC * HD];     // 12.8 KB
    __shared__ float red[4];

    const int g = blockIdx.x, tid = threadIdx.x;
    const int lane = tid & 63, wid = tid >> 6;

    // sum xp partials
    for (int i = tid; i < HD * KC; i += 256) {
        float v = 0.f;
        #pragma unroll
        for (int c = 0; c < NCH; ++c) v += g_PTp[(g * NCH + c) * HD * KC + i];
        PT[i] = v;
    }
    // ||G||^2 partial (sum chunk partials first, then square)
    float sumG2 = 0.f;
    for (int i = tid; i < KC * KC; i += 256) {
        float v = 0.f;
        #pragma unroll
        for (int c = 0; c < NCH; ++c) v += g_Gp[(g * NCH + c) * KC * KC + i];
        sumG2 += v * v;
        Ap[i] = g_Ap[(size_t)g * KC * KC + i];
    }
    __syncthreads();

    // h2 = xp + Ap @ xp   (PT[d][k] = xp[k][d])
    for (int k = wid; k < KC; k += 4) {
        float a = PT[lane * KC + k];
        #pragma unroll
        for (int l = 0; l < KC; ++l)
            a += Ap[k * KC + l] * PT[lane * KC + l];
        h2[k * HD + lane] = a;
    }
    __syncthreads();

    // t = relu(h2 @ W2a + b2a)
    {
        float wr[HD];
        #pragma unroll
        for (int d = 0; d < HD; ++d) wr[d] = W2a[d * HD + lane];
        float br = b2a[lane];
        for (int k = wid; k < KC; k += 4) {
            float a0 = br, a1 = 0.f, a2 = 0.f, a3 = 0.f;
            const float4* h4 = (const float4*)&h2[k * HD];
            #pragma unroll
            for (int i = 0; i < 16; ++i) {
                float4 v = h4[i];
                a0 += v.x * wr[4*i]; a1 += v.y * wr[4*i+1];
                a2 += v.z * wr[4*i+2]; a3 += v.w * wr[4*i+3];
            }
            tt[k * HD + lane] = fmaxf((a0 + a1) + (a2 + a3), 0.f);
        }
    }
    __syncthreads();

    // h3 = t @ W2b + b2b; fold mean over k and Wl into logits partials
    float l0 = 0.f, l1 = 0.f;
    {
        float wr[HD];
        #pragma unroll
        for (int j = 0; j < HD; ++j) wr[j] = W2b[j * HD + lane];
        float br = b2b[lane];
        float wl0 = Wl[lane * 2], wl1 = Wl[lane * 2 + 1];
        for (int k = wid; k < KC; k += 4) {
            float a0 = br, a1 = 0.f, a2 = 0.f, a3 = 0.f;
            const float4* t4 = (const float4*)&tt[k * HD];
            #pragma unroll
            for (int i = 0; i < 16; ++i) {
                float4 v = t4[i];
                a0 += v.x * wr[4*i]; a1 += v.y * wr[4*i+1];
                a2 += v.z * wr[4*i+2]; a3 += v.w * wr[4*i+3];
            }
            float a = (a0 + a1) + (a2 + a3);
            l0 += a * wl0; l1 += a * wl1;
        }
    }

    float rG2 = blockReduceN(sumG2, red, 4);
    float rl0 = blockReduceN(l0, red, 4);
    float rl1 = blockReduceN(l1, red, 4);
    if (tid == 0) {
        atomicAdd(&ws[3], rG2);
        float g0 = bl[0] + rl0 * (1.f / KC);
        float g1 = bl[1] + rl1 * (1.f / KC);
        float mm = fmaxf(g0, g1);
        float lse = mm + logf(expf(g0 - mm) + expf(g1 - mm));
        out[2 * g]     = g0 - lse;
        out[2 * g + 1] = g1 - lse;
    }
}

extern "C" void kernel_launch(void* const* d_in, const int* in_sizes, int n_in,
                              void* d_out, int out_size, void* d_ws, size_t ws_size,
                              hipStream_t stream) {
    const float* x    = (const float*)d_in[0];
    const float* W1a  = (const float*)d_in[1];
    const float* b1a  = (const float*)d_in[2];
    const float* W1b  = (const float*)d_in[3];
    const float* b1b  = (const float*)d_in[4];
    const float* Wp   = (const float*)d_in[5];
    const float* bp   = (const float*)d_in[6];
    const float* W2a  = (const float*)d_in[7];
    const float* b2a  = (const float*)d_in[8];
    const float* W2b  = (const float*)d_in[9];
    const float* b2b  = (const float*)d_in[10];
    const float* Wl   = (const float*)d_in[11];
    const float* bl   = (const float*)d_in[12];
    const int*   eidx = (const int*)d_in[13];   // [2, E] int32
    float* out = (float*)d_out;
    float* ws  = (float*)d_ws;

    zero_ws<<<1, 64, 0, stream>>>(ws);
    k1_edges<<<NG, 512, 0, stream>>>(eidx, eidx + ETOT, x, ws);
    k2_mlp<<<NG * NCH, 512, 0, stream>>>(W1a, b1a, W1b, b1b, Wp, bp, ws);
    k3_as<<<NG, 512, 0, stream>>>(ws);
    k4_head<<<NG, 256, 0, stream>>>(W2a, b2a, W2b, b2b, Wl, bl, out, ws);
    finalize_k<<<1, 64, 0, stream>>>(ws, out);
}

// Round 6
// 591.248 us; speedup vs baseline: 4.8856x; 2.2077x over previous
//
#include <hip/hip_runtime.h>
#include <math.h>

// Problem constants (from reference)
#define NG   1024        // graphs
#define NP   256         // nodes per graph
#define EPG  4096        // edges per graph
#define ETOT 4194304     // total edges
#define NTOT (NG * NP)   // 262144 nodes
#define FIN  7
#define HD   64
#define KC   50
#define SP   50          // packed row stride for g_S / k3
#define CHK  64          // rows per K2 chunk
#define NCH  4           // chunks per graph
#define FST  72          // f16 LDS row stride (144 B rows -> every row 16B-aligned)

// NOTE (R2): __launch_bounds__ 2nd arg acts as CUDA-style min BLOCKS/CU;
// (512,2) => 128-VGPR cap. Keep per-lane arrays small.
// NOTE (R3): LDS atomic scatter was 1215 us -> counting-sort gather in k1.
// NOTE (R4): persistent per-lane arrays spill at 128 VGPR -> wave-row regs.
// NOTE (R5): k2's GEMV-style phases were latency-bound (1 FMA per LDS float).
// -> f16 MFMA (16x16x32) for all four GEMMs, fp32 accumulate.

typedef __attribute__((ext_vector_type(8))) _Float16 v8h;
typedef __attribute__((ext_vector_type(4))) float v4f;

// Inter-kernel intermediates as statics: no hipMalloc, graph-capture safe.
__device__ float g_xagg[NTOT * 8];                  // x+agg, padded to 8
__device__ float g_S[NTOT * SP];                    // S rows, fp32, packed 50
__device__ unsigned char g_sdi[ETOT];               // di list, sorted by si
__device__ unsigned int g_roff[NG * 256];           // exclusive row offsets
__device__ float g_PTp[(size_t)NG * NCH * KC * HD]; // xp partials [k][d]
__device__ float g_Gp[(size_t)NG * NCH * KC * KC];  // G partials [k][c]
__device__ float g_Ap[(size_t)NG * KC * KC];        // Ap [k][c]

__global__ void zero_ws(float* ws) {
    if (threadIdx.x < 4) ws[threadIdx.x] = 0.f;
}

// ws[0]=sumA2, ws[1]=sum S logS, ws[2]=trace(Ap)=sum(A.SSt), ws[3]=||G||^2
__global__ void finalize_k(const float* __restrict__ ws, float* __restrict__ out) {
    if (threadIdx.x == 0) {
        float num = ws[0] - 2.f * ws[2] + ws[3];
        float link = sqrtf(fmaxf(num, 0.f)) / 67108864.0f;   // / (B*n*n)
        float ent  = -ws[1] / 262144.0f;                     // / N
        out[2048] = link + ent;
    }
}

__device__ __forceinline__ float blockReduceN(float v, float* red, int nw) {
    __syncthreads();
    #pragma unroll
    for (int o = 32; o > 0; o >>= 1) v += __shfl_down(v, o);
    if ((threadIdx.x & 63) == 0) red[threadIdx.x >> 6] = v;
    __syncthreads();
    float r = 0.f;
    if (threadIdx.x == 0) {
        for (int i = 0; i < nw; ++i) r += red[i];
    }
    return r;
}

// ---- K1: edges -> cells, sum(A^2), si-counting-sort, GIN aggregation --------
__launch_bounds__(512, 2)
__global__ void k1_edges(const int* __restrict__ esrc, const int* __restrict__ edst,
                         const float* __restrict__ x, float* __restrict__ ws)
{
    __shared__ unsigned int cnt[8192];          // 32 KB (two u16 counters / word)
    __shared__ unsigned short cells[EPG];       // 8 KB
    __shared__ unsigned char sdi[EPG];          // 4 KB
    __shared__ unsigned int hist[256], roff[256], cursor[256];
    __shared__ float xt[NP * FIN];              // 7 KB
    __shared__ float agg[NP * FIN];             // 7 KB
    __shared__ float red[8];

    const int g = blockIdx.x, tid = threadIdx.x;
    const int lane = tid & 63, wid = tid >> 6;

    for (int e = tid; e < EPG; e += 512) {
        int s = esrc[g * EPG + e] & (NP - 1);
        int d = edst[g * EPG + e] & (NP - 1);
        cells[e] = (unsigned short)((s << 8) | d);
    }
    for (int i = tid; i < NP * FIN; i += 512) {
        xt[i]  = x[g * NP * FIN + i];
        agg[i] = 0.f;
    }
    if (tid < 256) hist[tid] = 0u;
    __syncthreads();

    float sumA2 = 0.f;
    for (int ch = 0; ch < 4; ++ch) {
        for (int i = tid; i < 8192; i += 512) cnt[i] = 0u;
        __syncthreads();
        int base = ch << 14;
        for (int e = tid; e < EPG; e += 512) {
            int c = cells[e];
            int r = c - base;
            if ((unsigned)r < 16384u)
                atomicAdd(&cnt[r >> 1], (r & 1) ? 0x10000u : 1u);
            if (ch == 0) atomicAdd(&hist[c >> 8], 1u);
        }
        __syncthreads();
        for (int i = tid; i < 8192; i += 512) {
            unsigned v = cnt[i];
            float m0 = (float)(v & 0xffffu), m1 = (float)(v >> 16);
            sumA2 += m0 * m0 + m1 * m1;
        }
        __syncthreads();
    }

    if (wid == 0) {
        unsigned carry = 0;
        for (int c = 0; c < 4; ++c) {
            unsigned v = hist[c * 64 + lane];
            unsigned s = v;
            #pragma unroll
            for (int o = 1; o < 64; o <<= 1) {
                unsigned t = __shfl_up(s, o);
                if (lane >= o) s += t;
            }
            unsigned excl = s - v + carry;
            roff[c * 64 + lane] = excl;
            cursor[c * 64 + lane] = excl;
            carry += __shfl(s, 63);
        }
    }
    __syncthreads();

    for (int e = tid; e < EPG; e += 512) {
        int c = cells[e];
        unsigned pos = atomicAdd(&cursor[c >> 8], 1u);
        sdi[pos] = (unsigned char)(c & 255);
    }

    for (int e = tid; e < EPG; e += 512) {
        int c = cells[e]; int si = c >> 8, di = c & 255;
        #pragma unroll
        for (int f = 0; f < FIN; ++f)
            atomicAdd(&agg[di * FIN + f], xt[si * FIN + f]);
    }
    __syncthreads();

    for (int i = tid; i < NP * 8; i += 512) {
        int n = i >> 3, f = i & 7;
        float v = (f < FIN) ? (xt[n * FIN + f] + agg[n * FIN + f]) : 0.f;
        g_xagg[g * NP * 8 + i] = v;
    }
    for (int i = tid; i < EPG / 4; i += 512)
        ((unsigned int*)g_sdi)[g * (EPG / 4) + i] = ((const unsigned int*)sdi)[i];
    if (tid < 256) g_roff[g * 256 + tid] = roff[tid];

    float r = blockReduceN(sumA2, red, 8);
    if (tid == 0) atomicAdd(&ws[0], r);
}

// ---- K2: MFMA f16 — MLP1, h-GEMM, P-GEMM, softmax, xp/G-GEMMs ---------------
// LDS ~72.5 KB -> 2 blocks/CU. 128 MFMA/block replaces ~3300 VALU FMAs.
__launch_bounds__(512, 2)
__global__ void k2_mlp(const float* __restrict__ W1a, const float* __restrict__ b1a,
                       const float* __restrict__ W1b, const float* __restrict__ b1b,
                       const float* __restrict__ Wp,  const float* __restrict__ bp,
                       float* __restrict__ ws)
{
    __shared__ __align__(16) float xt[CHK * 8];          // 2 KB
    __shared__ __align__(16) _Float16 t1b[CHK * FST];    // 9.2 KB  t1   [n][j]
    __shared__ __align__(16) _Float16 W1bT[HD * FST];    // 9.2 KB  W1b^T[d][j]
    __shared__ __align__(16) _Float16 WpT[HD * FST];     // 9.2 KB  Wp^T [k][d] (k<50 valid)
    __shared__ __align__(16) _Float16 hN[CHK * FST];     // 9.2 KB  h    [n][d]
    __shared__ __align__(16) _Float16 hT[HD * FST];      // 9.2 KB  h^T  [d][n]
    __shared__ __align__(16) _Float16 StT[HD * FST];     // 9.2 KB  S^T  [k][n] (k<50 valid)
    __shared__ __align__(16) float Pf[CHK * 66];         // 16.9 KB P    [n][k]
    __shared__ float red[8];

    const int b = blockIdx.x, rbase = b * CHK, tid = threadIdx.x;
    const int lane = tid & 63, wid = tid >> 6;
    const int l15 = lane & 15, quad = lane >> 4;
    const int fko = quad * 8;                            // frag k-offset within 32

    // stage x+agg and transposed weights (f16)
    xt[tid] = g_xagg[rbase * 8 + tid];
    for (int i = tid; i < HD * HD; i += 512) {           // W1b[j][d] -> W1bT[d][j]
        int j = i >> 6, d = i & 63;
        W1bT[d * FST + j] = (_Float16)W1b[i];
    }
    for (int i = tid; i < HD * KC; i += 512) {           // Wp[d][k] -> WpT[k][d]
        int d = i / KC, k = i - d * KC;
        WpT[k * FST + d] = (_Float16)Wp[i];
    }
    __syncthreads();

    // t1 = relu((x+agg) @ W1a + b1a), f16 [n][j]
    {
        float w1r[FIN];
        #pragma unroll
        for (int f = 0; f < FIN; ++f) w1r[f] = W1a[f * HD + lane];
        float br = b1a[lane];
        for (int n = wid; n < CHK; n += 8) {
            float a = br;
            #pragma unroll
            for (int f = 0; f < FIN; ++f) a += xt[n * 8 + f] * w1r[f];
            t1b[n * FST + lane] = (_Float16)fmaxf(a, 0.f);
        }
    }
    __syncthreads();

    // h = t1 @ W1b + b1b  ->  hN [n][d], hT [d][n]   (16 tiles, 2/wave)
    for (int t = wid * 2; t < wid * 2 + 2; ++t) {
        int mt = (t >> 2) << 4, nt = (t & 3) << 4;
        v4f acc = {0.f, 0.f, 0.f, 0.f};
        #pragma unroll
        for (int ks = 0; ks < 2; ++ks) {
            v8h af = *(const v8h*)&t1b[(mt + l15) * FST + ks * 32 + fko];
            v8h bf = *(const v8h*)&W1bT[(nt + l15) * FST + ks * 32 + fko];
            acc = __builtin_amdgcn_mfma_f32_16x16x32_f16(af, bf, acc, 0, 0, 0);
        }
        int d = nt + l15;
        float bv = b1b[d];
        #pragma unroll
        for (int r = 0; r < 4; ++r) {
            int m = mt + quad * 4 + r;
            _Float16 hv = (_Float16)(acc[r] + bv);
            hN[m * FST + d] = hv;
            hT[d * FST + m] = hv;
        }
    }
    __syncthreads();

    // P = h @ Wp + bp -> Pf [n][k]  (cols >= 50 never written/read)
    for (int t = wid * 2; t < wid * 2 + 2; ++t) {
        int mt = (t >> 2) << 4, nt = (t & 3) << 4;
        v4f acc = {0.f, 0.f, 0.f, 0.f};
        #pragma unroll
        for (int ks = 0; ks < 2; ++ks) {
            v8h af = *(const v8h*)&hN[(mt + l15) * FST + ks * 32 + fko];
            v8h bf = *(const v8h*)&WpT[(nt + l15) * FST + ks * 32 + fko];
            acc = __builtin_amdgcn_mfma_f32_16x16x32_f16(af, bf, acc, 0, 0, 0);
        }
        int kcol = nt + l15;
        if (kcol < KC) {
            float bv = bp[kcol];
            #pragma unroll
            for (int r = 0; r < 4; ++r)
                Pf[(mt + quad * 4 + r) * 66 + kcol] = acc[r] + bv;
        }
    }
    __syncthreads();

    // softmax rows -> StT f16 [k][n], g_S fp32, entropy partial
    float entL = 0.f;
    for (int n = wid; n < CHK; n += 8) {
        float a = (lane < KC) ? Pf[n * 66 + lane] : -INFINITY;
        float m = a;
        #pragma unroll
        for (int o = 32; o > 0; o >>= 1) m = fmaxf(m, __shfl_xor(m, o));
        float e = expf(a - m);
        float ss = e;
        #pragma unroll
        for (int o = 32; o > 0; o >>= 1) ss += __shfl_xor(ss, o);
        float s = e / ss;
        if (lane < KC) {
            StT[lane * FST + n] = (_Float16)s;
            g_S[(size_t)(rbase + n) * SP + lane] = s;
            entL += s * logf(s + 1e-15f);
        }
    }
    __syncthreads();

    // xp = S^T h -> g_PTp [k][d] ; G = S^T S -> g_Gp [k][c]  (fused, shared A)
    for (int t = wid * 2; t < wid * 2 + 2; ++t) {
        int mt = (t >> 2) << 4, nt = (t & 3) << 4;
        v4f axp = {0.f, 0.f, 0.f, 0.f};
        v4f ag  = {0.f, 0.f, 0.f, 0.f};
        #pragma unroll
        for (int ks = 0; ks < 2; ++ks) {
            v8h af = *(const v8h*)&StT[(mt + l15) * FST + ks * 32 + fko];
            v8h bh = *(const v8h*)&hT[(nt + l15) * FST + ks * 32 + fko];
            v8h bs = *(const v8h*)&StT[(nt + l15) * FST + ks * 32 + fko];
            axp = __builtin_amdgcn_mfma_f32_16x16x32_f16(af, bh, axp, 0, 0, 0);
            ag  = __builtin_amdgcn_mfma_f32_16x16x32_f16(af, bs, ag, 0, 0, 0);
        }
        int col = nt + l15;
        #pragma unroll
        for (int r = 0; r < 4; ++r) {
            int row = mt + quad * 4 + r;
            if (row < KC) {
                g_PTp[(size_t)b * (KC * HD) + row * HD + col] = axp[r];
                if (col < KC)
                    g_Gp[(size_t)b * (KC * KC) + row * KC + col] = ag[r];
            }
        }
    }

    float r = blockReduceN(entL, red, 8);
    if (tid == 0) atomicAdd(&ws[1], r);
}

// ---- K3: AS by sorted gather (quarters) + wave-row Ap + trace(Ap) -----------
__launch_bounds__(512, 2)
__global__ void k3_as(float* __restrict__ ws)
{
    __shared__ __align__(16) float St[NP * SP];       // 50 KB, packed stride 50
    __shared__ __align__(16) float ASq[64 * SP];      // 12.5 KB (quarter of AS)
    __shared__ __align__(16) unsigned char sdi[EPG];  // 4 KB
    __shared__ unsigned int roff[NP + 1];             // 1 KB
    __shared__ float red[8];

    const int g = blockIdx.x, tid = threadIdx.x;
    const int lane = tid & 63, wid = tid >> 6;
    const int cc = (lane < SP) ? lane : (SP - 1);

    for (int i = tid; i < NP * SP / 4; i += 512)
        ((float4*)St)[i] = ((const float4*)(g_S + (size_t)g * NP * SP))[i];
    for (int i = tid; i < EPG / 4; i += 512)
        ((unsigned int*)sdi)[i] = ((const unsigned int*)g_sdi)[g * (EPG / 4) + i];
    if (tid < NP) roff[tid] = g_roff[g * NP + tid];
    if (tid == NP) roff[NP] = EPG;
    __syncthreads();

    float ap[7];
    #pragma unroll
    for (int j = 0; j < 7; ++j) ap[j] = 0.f;

    for (int q = 0; q < 4; ++q) {
        for (int rr = wid * 8; rr < wid * 8 + 8; ++rr) {
            int n = q * 64 + rr;
            int beg = roff[n], end = roff[n + 1];
            float acc = 0.f;
            for (int e = beg; e < end; ++e)
                acc += St[sdi[e] * SP + cc];
            if (lane < SP) ASq[rr * SP + lane] = acc;
        }
        __syncthreads();

        for (int n = 0; n < 64; ++n) {
            float as = ASq[n * SP + cc];
            const float* sr = &St[(q * 64 + n) * SP];
            #pragma unroll
            for (int j = 0; j < 7; ++j) {
                int k = wid + j * 8;
                int kcl = (k < SP) ? k : (SP - 1);
                ap[j] += sr[kcl] * as;
            }
        }
        __syncthreads();
    }

    float tr = 0.f;
    #pragma unroll
    for (int j = 0; j < 7; ++j) {
        int k = wid + j * 8;
        if (k < SP && lane < SP) {
            g_Ap[(size_t)g * SP * SP + k * SP + lane] = ap[j];
            if (lane == k) tr += ap[j];
        }
    }

    float r = blockReduceN(tr, red, 8);
    if (tid == 0) atomicAdd(&ws[2], r);
}

// ---- K4: combine partials, ||G||^2, dense GIN, classifier -------------------
__launch_bounds__(256, 3)
__global__ void k4_head(const float* __restrict__ W2a, const float* __restrict__ b2a,
                        const float* __restrict__ W2b, const float* __restrict__ b2b,
                        const float* __restrict__ Wl,  const float* __restrict__ bl,
                        float* __restrict__ out, float* __restrict__ ws)
{
    __shared__ __align__(16) float xpL[KC * HD];    // 12.8 KB  xp [k][d]
    __shared__ __align__(16) float Ap[KC * KC];     // 10 KB
    __shared__ __align__(16) float h2[KC * HD];     // 12.8 KB
    __shared__ __align__(16) float tt[KC * HD];     // 12.8 KB
    __shared__ float red[4];

    const int g = blockIdx.x, tid = threadIdx.x;
    const int lane = tid & 63, wid = tid >> 6;

    for (int i = tid; i < KC * HD; i += 256) {
        float v = 0.f;
        #pragma unroll
        for (int c = 0; c < NCH; ++c)
            v += g_PTp[(size_t)(g * NCH + c) * (KC * HD) + i];
        xpL[i] = v;
    }
    float sumG2 = 0.f;
    for (int i = tid; i < KC * KC; i += 256) {
        float v = 0.f;
        #pragma unroll
        for (int c = 0; c < NCH; ++c)
            v += g_Gp[(size_t)(g * NCH + c) * (KC * KC) + i];
        sumG2 += v * v;
        Ap[i] = g_Ap[(size_t)g * KC * KC + i];
    }
    __syncthreads();

    // h2[k][d] = xp[k][d] + sum_l Ap[k][l] * xp[l][d]
    for (int k = wid; k < KC; k += 4) {
        float a = xpL[k * HD + lane];
        #pragma unroll
        for (int l = 0; l < KC; ++l)
            a += Ap[k * KC + l] * xpL[l * HD + lane];
        h2[k * HD + lane] = a;
    }
    __syncthreads();

    // t = relu(h2 @ W2a + b2a)
    {
        float wr[HD];
        #pragma unroll
        for (int d = 0; d < HD; ++d) wr[d] = W2a[d * HD + lane];
        float br = b2a[lane];
        for (int k = wid; k < KC; k += 4) {
            float a0 = br, a1 = 0.f, a2 = 0.f, a3 = 0.f;
            const float4* h4 = (const float4*)&h2[k * HD];
            #pragma unroll
            for (int i = 0; i < 16; ++i) {
                float4 v = h4[i];
                a0 += v.x * wr[4*i]; a1 += v.y * wr[4*i+1];
                a2 += v.z * wr[4*i+2]; a3 += v.w * wr[4*i+3];
            }
            tt[k * HD + lane] = fmaxf((a0 + a1) + (a2 + a3), 0.f);
        }
    }
    __syncthreads();

    // h3 = t @ W2b + b2b; fold mean over k and Wl into logits partials
    float l0 = 0.f, l1 = 0.f;
    {
        float wr[HD];
        #pragma unroll
        for (int j = 0; j < HD; ++j) wr[j] = W2b[j * HD + lane];
        float br = b2b[lane];
        float wl0 = Wl[lane * 2], wl1 = Wl[lane * 2 + 1];
        for (int k = wid; k < KC; k += 4) {
            float a0 = br, a1 = 0.f, a2 = 0.f, a3 = 0.f;
            const float4* t4 = (const float4*)&tt[k * HD];
            #pragma unroll
            for (int i = 0; i < 16; ++i) {
                float4 v = t4[i];
                a0 += v.x * wr[4*i]; a1 += v.y * wr[4*i+1];
                a2 += v.z * wr[4*i+2]; a3 += v.w * wr[4*i+3];
            }
            float a = (a0 + a1) + (a2 + a3);
            l0 += a * wl0; l1 += a * wl1;
        }
    }

    float rG2 = blockReduceN(sumG2, red, 4);
    float rl0 = blockReduceN(l0, red, 4);
    float rl1 = blockReduceN(l1, red, 4);
    if (tid == 0) {
        atomicAdd(&ws[3], rG2);
        float g0 = bl[0] + rl0 * (1.f / KC);
        float g1 = bl[1] + rl1 * (1.f / KC);
        float mm = fmaxf(g0, g1);
        float lse = mm + logf(expf(g0 - mm) + expf(g1 - mm));
        out[2 * g]     = g0 - lse;
        out[2 * g + 1] = g1 - lse;
    }
}

extern "C" void kernel_launch(void* const* d_in, const int* in_sizes, int n_in,
                              void* d_out, int out_size, void* d_ws, size_t ws_size,
                              hipStream_t stream) {
    const float* x    = (const float*)d_in[0];
    const float* W1a  = (const float*)d_in[1];
    const float* b1a  = (const float*)d_in[2];
    const float* W1b  = (const float*)d_in[3];
    const float* b1b  = (const float*)d_in[4];
    const float* Wp   = (const float*)d_in[5];
    const float* bp   = (const float*)d_in[6];
    const float* W2a  = (const float*)d_in[7];
    const float* b2a  = (const float*)d_in[8];
    const float* W2b  = (const float*)d_in[9];
    const float* b2b  = (const float*)d_in[10];
    const float* Wl   = (const float*)d_in[11];
    const float* bl   = (const float*)d_in[12];
    const int*   eidx = (const int*)d_in[13];   // [2, E] int32
    float* out = (float*)d_out;
    float* ws  = (float*)d_ws;

    zero_ws<<<1, 64, 0, stream>>>(ws);
    k1_edges<<<NG, 512, 0, stream>>>(eidx, eidx + ETOT, x, ws);
    k2_mlp<<<NG * NCH, 512, 0, stream>>>(W1a, b1a, W1b, b1b, Wp, bp, ws);
    k3_as<<<NG, 512, 0, stream>>>(ws);
    k4_head<<<NG, 256, 0, stream>>>(W2a, b2a, W2b, b2b, Wl, bl, out, ws);
    finalize_k<<<1, 64, 0, stream>>>(ws, out);
}

// Round 7
// 499.971 us; speedup vs baseline: 5.7776x; 1.1826x over previous
//
#include <hip/hip_runtime.h>
#include <math.h>

// Problem constants (from reference)
#define NG   1024        // graphs
#define NP   256         // nodes per graph
#define EPG  4096        // edges per graph
#define ETOT 4194304     // total edges
#define NTOT (NG * NP)   // 262144 nodes
#define FIN  7
#define HD   64
#define KC   50
#define SP   50          // packed row stride for g_S / k3
#define CHK  64          // rows per K2 chunk
#define NCH  4           // chunks per graph
#define FST  72          // f16 LDS row stride (144 B rows -> every row 16B-aligned)

// NOTE (R2): __launch_bounds__ 2nd arg acts as CUDA-style min BLOCKS/CU;
// (512,2) => 128-VGPR cap. Keep per-lane arrays small.
// NOTE (R3): LDS atomic scatter was 1215 us -> counting-sort gather in k1.
// NOTE (R4): persistent per-lane arrays spill at 128 VGPR -> wave-row regs.
// NOTE (R5): GEMV-style phases are latency-bound (1 FMA per LDS float)
// -> f16 MFMA (16x16x32) for all four k2 GEMMs, fp32 accumulate.
// NOTE (R6): k1 was serial-phase/latency-bound (12 barriers, 28K scatter
// atomics, 1024 blocks). Split: k1b counts A^2 chunks at 4096 blocks;
// k1a dual counting-sort + gather agg, 3 blocks/CU.

typedef __attribute__((ext_vector_type(8))) _Float16 v8h;
typedef __attribute__((ext_vector_type(4))) float v4f;

// Inter-kernel intermediates as statics: no hipMalloc, graph-capture safe.
__device__ float g_xagg[NTOT * 8];                  // x+agg, padded to 8
__device__ float g_S[NTOT * SP];                    // S rows, fp32, packed 50
__device__ unsigned char g_sdi[ETOT];               // di list, sorted by si
__device__ unsigned int g_roff[NG * 256];           // exclusive si-row offsets
__device__ float g_PTp[(size_t)NG * NCH * KC * HD]; // xp partials [k][d]
__device__ float g_Gp[(size_t)NG * NCH * KC * KC];  // G partials [k][c]
__device__ float g_Ap[(size_t)NG * KC * KC];        // Ap [k][c]

__global__ void zero_ws(float* ws) {
    if (threadIdx.x < 4) ws[threadIdx.x] = 0.f;
}

// ws[0]=sumA2, ws[1]=sum S logS, ws[2]=trace(Ap)=sum(A.SSt), ws[3]=||G||^2
__global__ void finalize_k(const float* __restrict__ ws, float* __restrict__ out) {
    if (threadIdx.x == 0) {
        float num = ws[0] - 2.f * ws[2] + ws[3];
        float link = sqrtf(fmaxf(num, 0.f)) / 67108864.0f;   // / (B*n*n)
        float ent  = -ws[1] / 262144.0f;                     // / N
        out[2048] = link + ent;
    }
}

__device__ __forceinline__ float blockReduceN(float v, float* red, int nw) {
    __syncthreads();
    #pragma unroll
    for (int o = 32; o > 0; o >>= 1) v += __shfl_down(v, o);
    if ((threadIdx.x & 63) == 0) red[threadIdx.x >> 6] = v;
    __syncthreads();
    float r = 0.f;
    if (threadIdx.x == 0) {
        for (int i = 0; i < nw; ++i) r += red[i];
    }
    return r;
}

// ---- K1a: dual counting sort (si->di for k3, di->si for agg) + gather agg ---
// LDS ~31 KB -> 3 blocks/CU
__launch_bounds__(512, 3)
__global__ void k1a_sort(const int* __restrict__ esrc, const int* __restrict__ edst,
                         const float* __restrict__ x)
{
    __shared__ unsigned short cells[EPG];       // 8 KB
    __shared__ unsigned char sdi[EPG];          // 4 KB  (si-sorted di)
    __shared__ unsigned char ssi[EPG];          // 4 KB  (di-sorted si)
    __shared__ float xt8[NP * 8];               // 8 KB  (x, stride 8, pad 0)
    __shared__ unsigned int hist_si[256], roff_si[256], cur_si[256];
    __shared__ unsigned int hist_di[256], cur_di[256];
    __shared__ unsigned int roff_di[NP + 1];

    const int g = blockIdx.x, tid = threadIdx.x;
    const int lane = tid & 63, wid = tid >> 6;

    if (tid < 256) { hist_si[tid] = 0u; hist_di[tid] = 0u; }
    __syncthreads();

    for (int e = tid; e < EPG; e += 512) {
        int s = esrc[g * EPG + e] & (NP - 1);
        int d = edst[g * EPG + e] & (NP - 1);
        cells[e] = (unsigned short)((s << 8) | d);
        atomicAdd(&hist_si[s], 1u);
        atomicAdd(&hist_di[d], 1u);
    }
    for (int i = tid; i < NP * 8; i += 512) {
        int n = i >> 3, f = i & 7;
        xt8[i] = (f < FIN) ? x[g * NP * FIN + n * FIN + f] : 0.f;
    }
    __syncthreads();

    // parallel exclusive scans: wave 0 -> si, wave 1 -> di
    if (wid == 0) {
        unsigned carry = 0;
        for (int c = 0; c < 4; ++c) {
            unsigned v = hist_si[c * 64 + lane];
            unsigned s = v;
            #pragma unroll
            for (int o = 1; o < 64; o <<= 1) {
                unsigned t = __shfl_up(s, o);
                if (lane >= o) s += t;
            }
            unsigned excl = s - v + carry;
            roff_si[c * 64 + lane] = excl;
            cur_si[c * 64 + lane] = excl;
            carry += __shfl(s, 63);
        }
    } else if (wid == 1) {
        unsigned carry = 0;
        for (int c = 0; c < 4; ++c) {
            unsigned v = hist_di[c * 64 + lane];
            unsigned s = v;
            #pragma unroll
            for (int o = 1; o < 64; o <<= 1) {
                unsigned t = __shfl_up(s, o);
                if (lane >= o) s += t;
            }
            unsigned excl = s - v + carry;
            roff_di[c * 64 + lane] = excl;
            cur_di[c * 64 + lane] = excl;
            carry += __shfl(s, 63);
        }
        if (lane == 0) roff_di[NP] = EPG;
    }
    __syncthreads();

    // placement for both sorts
    for (int e = tid; e < EPG; e += 512) {
        int c = cells[e]; int si = c >> 8, di = c & 255;
        unsigned p1 = atomicAdd(&cur_si[si], 1u);
        sdi[p1] = (unsigned char)di;
        unsigned p2 = atomicAdd(&cur_di[di], 1u);
        ssi[p2] = (unsigned char)si;
    }
    __syncthreads();

    // persist si-sorted list + offsets for k3
    for (int i = tid; i < EPG / 4; i += 512)
        ((unsigned int*)g_sdi)[g * (EPG / 4) + i] = ((const unsigned int*)sdi)[i];
    if (tid < 256) g_roff[g * 256 + tid] = roff_si[tid];

    // gather agg: 8 lanes per node (f = lane&7), write x+agg
    {
        const int gidx = tid >> 3, f = tid & 7;
        for (int n = gidx; n < NP; n += 64) {
            int beg = roff_di[n], end = roff_di[n + 1];
            float a = xt8[n * 8 + f];
            for (int e = beg; e < end; ++e)
                a += xt8[ssi[e] * 8 + f];
            g_xagg[g * NP * 8 + n * 8 + f] = a;
        }
    }
}

// ---- K1b: sum(A^2) dense counts, 4 blocks per graph (parallel chunks) -------
// LDS 32 KB -> 2+ blocks/CU, 4096 blocks
__launch_bounds__(512, 2)
__global__ void k1b_a2(const int* __restrict__ esrc, const int* __restrict__ edst,
                       float* __restrict__ ws)
{
    __shared__ unsigned int cnt[8192];          // 32 KB (two u16 counters / word)
    __shared__ float red[8];

    const int g = blockIdx.x >> 2, ch = blockIdx.x & 3, tid = threadIdx.x;

    for (int i = tid; i < 8192; i += 512) cnt[i] = 0u;
    __syncthreads();

    int base = ch << 14;
    for (int e = tid; e < EPG; e += 512) {
        int s = esrc[g * EPG + e] & (NP - 1);
        int d = edst[g * EPG + e] & (NP - 1);
        int r = ((s << 8) | d) - base;
        if ((unsigned)r < 16384u)
            atomicAdd(&cnt[r >> 1], (r & 1) ? 0x10000u : 1u);
    }
    __syncthreads();

    float sumA2 = 0.f;
    for (int i = tid; i < 8192; i += 512) {
        unsigned v = cnt[i];
        float m0 = (float)(v & 0xffffu), m1 = (float)(v >> 16);
        sumA2 += m0 * m0 + m1 * m1;
    }

    float r = blockReduceN(sumA2, red, 8);
    if (tid == 0) atomicAdd(&ws[0], r);
}

// ---- K2: MFMA f16 — MLP1, h-GEMM, P-GEMM, softmax, xp/G-GEMMs ---------------
// LDS ~72.5 KB -> 2 blocks/CU. 128 MFMA/block replaces ~3300 VALU FMAs.
__launch_bounds__(512, 2)
__global__ void k2_mlp(const float* __restrict__ W1a, const float* __restrict__ b1a,
                       const float* __restrict__ W1b, const float* __restrict__ b1b,
                       const float* __restrict__ Wp,  const float* __restrict__ bp,
                       float* __restrict__ ws)
{
    __shared__ __align__(16) float xt[CHK * 8];          // 2 KB
    __shared__ __align__(16) _Float16 t1b[CHK * FST];    // 9.2 KB  t1   [n][j]
    __shared__ __align__(16) _Float16 W1bT[HD * FST];    // 9.2 KB  W1b^T[d][j]
    __shared__ __align__(16) _Float16 WpT[HD * FST];     // 9.2 KB  Wp^T [k][d] (k<50 valid)
    __shared__ __align__(16) _Float16 hN[CHK * FST];     // 9.2 KB  h    [n][d]
    __shared__ __align__(16) _Float16 hT[HD * FST];      // 9.2 KB  h^T  [d][n]
    __shared__ __align__(16) _Float16 StT[HD * FST];     // 9.2 KB  S^T  [k][n] (k<50 valid)
    __shared__ __align__(16) float Pf[CHK * 66];         // 16.9 KB P    [n][k]
    __shared__ float red[8];

    const int b = blockIdx.x, rbase = b * CHK, tid = threadIdx.x;
    const int lane = tid & 63, wid = tid >> 6;
    const int l15 = lane & 15, quad = lane >> 4;
    const int fko = quad * 8;                            // frag k-offset within 32

    // stage x+agg and transposed weights (f16)
    xt[tid] = g_xagg[rbase * 8 + tid];
    for (int i = tid; i < HD * HD; i += 512) {           // W1b[j][d] -> W1bT[d][j]
        int j = i >> 6, d = i & 63;
        W1bT[d * FST + j] = (_Float16)W1b[i];
    }
    for (int i = tid; i < HD * KC; i += 512) {           // Wp[d][k] -> WpT[k][d]
        int d = i / KC, k = i - d * KC;
        WpT[k * FST + d] = (_Float16)Wp[i];
    }
    __syncthreads();

    // t1 = relu((x+agg) @ W1a + b1a), f16 [n][j]
    {
        float w1r[FIN];
        #pragma unroll
        for (int f = 0; f < FIN; ++f) w1r[f] = W1a[f * HD + lane];
        float br = b1a[lane];
        for (int n = wid; n < CHK; n += 8) {
            float a = br;
            #pragma unroll
            for (int f = 0; f < FIN; ++f) a += xt[n * 8 + f] * w1r[f];
            t1b[n * FST + lane] = (_Float16)fmaxf(a, 0.f);
        }
    }
    __syncthreads();

    // h = t1 @ W1b + b1b  ->  hN [n][d], hT [d][n]   (16 tiles, 2/wave)
    for (int t = wid * 2; t < wid * 2 + 2; ++t) {
        int mt = (t >> 2) << 4, nt = (t & 3) << 4;
        v4f acc = {0.f, 0.f, 0.f, 0.f};
        #pragma unroll
        for (int ks = 0; ks < 2; ++ks) {
            v8h af = *(const v8h*)&t1b[(mt + l15) * FST + ks * 32 + fko];
            v8h bf = *(const v8h*)&W1bT[(nt + l15) * FST + ks * 32 + fko];
            acc = __builtin_amdgcn_mfma_f32_16x16x32_f16(af, bf, acc, 0, 0, 0);
        }
        int d = nt + l15;
        float bv = b1b[d];
        #pragma unroll
        for (int r = 0; r < 4; ++r) {
            int m = mt + quad * 4 + r;
            _Float16 hv = (_Float16)(acc[r] + bv);
            hN[m * FST + d] = hv;
            hT[d * FST + m] = hv;
        }
    }
    __syncthreads();

    // P = h @ Wp + bp -> Pf [n][k]  (cols >= 50 never written/read)
    for (int t = wid * 2; t < wid * 2 + 2; ++t) {
        int mt = (t >> 2) << 4, nt = (t & 3) << 4;
        v4f acc = {0.f, 0.f, 0.f, 0.f};
        #pragma unroll
        for (int ks = 0; ks < 2; ++ks) {
            v8h af = *(const v8h*)&hN[(mt + l15) * FST + ks * 32 + fko];
            v8h bf = *(const v8h*)&WpT[(nt + l15) * FST + ks * 32 + fko];
            acc = __builtin_amdgcn_mfma_f32_16x16x32_f16(af, bf, acc, 0, 0, 0);
        }
        int kcol = nt + l15;
        if (kcol < KC) {
            float bv = bp[kcol];
            #pragma unroll
            for (int r = 0; r < 4; ++r)
                Pf[(mt + quad * 4 + r) * 66 + kcol] = acc[r] + bv;
        }
    }
    __syncthreads();

    // softmax rows -> StT f16 [k][n], g_S fp32, entropy partial
    float entL = 0.f;
    for (int n = wid; n < CHK; n += 8) {
        float a = (lane < KC) ? Pf[n * 66 + lane] : -INFINITY;
        float m = a;
        #pragma unroll
        for (int o = 32; o > 0; o >>= 1) m = fmaxf(m, __shfl_xor(m, o));
        float e = expf(a - m);
        float ss = e;
        #pragma unroll
        for (int o = 32; o > 0; o >>= 1) ss += __shfl_xor(ss, o);
        float s = e / ss;
        if (lane < KC) {
            StT[lane * FST + n] = (_Float16)s;
            g_S[(size_t)(rbase + n) * SP + lane] = s;
            entL += s * logf(s + 1e-15f);
        }
    }
    __syncthreads();

    // xp = S^T h -> g_PTp [k][d] ; G = S^T S -> g_Gp [k][c]  (fused, shared A)
    for (int t = wid * 2; t < wid * 2 + 2; ++t) {
        int mt = (t >> 2) << 4, nt = (t & 3) << 4;
        v4f axp = {0.f, 0.f, 0.f, 0.f};
        v4f ag  = {0.f, 0.f, 0.f, 0.f};
        #pragma unroll
        for (int ks = 0; ks < 2; ++ks) {
            v8h af = *(const v8h*)&StT[(mt + l15) * FST + ks * 32 + fko];
            v8h bh = *(const v8h*)&hT[(nt + l15) * FST + ks * 32 + fko];
            v8h bs = *(const v8h*)&StT[(nt + l15) * FST + ks * 32 + fko];
            axp = __builtin_amdgcn_mfma_f32_16x16x32_f16(af, bh, axp, 0, 0, 0);
            ag  = __builtin_amdgcn_mfma_f32_16x16x32_f16(af, bs, ag, 0, 0, 0);
        }
        int col = nt + l15;
        #pragma unroll
        for (int r = 0; r < 4; ++r) {
            int row = mt + quad * 4 + r;
            if (row < KC) {
                g_PTp[(size_t)b * (KC * HD) + row * HD + col] = axp[r];
                if (col < KC)
                    g_Gp[(size_t)b * (KC * KC) + row * KC + col] = ag[r];
            }
        }
    }

    float r = blockReduceN(entL, red, 8);
    if (tid == 0) atomicAdd(&ws[1], r);
}

// ---- K3: AS by sorted gather (quarters) + wave-row Ap + trace(Ap) -----------
__launch_bounds__(512, 2)
__global__ void k3_as(float* __restrict__ ws)
{
    __shared__ __align__(16) float St[NP * SP];       // 50 KB, packed stride 50
    __shared__ __align__(16) float ASq[64 * SP];      // 12.5 KB (quarter of AS)
    __shared__ __align__(16) unsigned char sdi[EPG];  // 4 KB
    __shared__ unsigned int roff[NP + 1];             // 1 KB
    __shared__ float red[8];

    const int g = blockIdx.x, tid = threadIdx.x;
    const int lane = tid & 63, wid = tid >> 6;
    const int cc = (lane < SP) ? lane : (SP - 1);

    for (int i = tid; i < NP * SP / 4; i += 512)
        ((float4*)St)[i] = ((const float4*)(g_S + (size_t)g * NP * SP))[i];
    for (int i = tid; i < EPG / 4; i += 512)
        ((unsigned int*)sdi)[i] = ((const unsigned int*)g_sdi)[g * (EPG / 4) + i];
    if (tid < NP) roff[tid] = g_roff[g * NP + tid];
    if (tid == NP) roff[NP] = EPG;
    __syncthreads();

    float ap[7];
    #pragma unroll
    for (int j = 0; j < 7; ++j) ap[j] = 0.f;

    for (int q = 0; q < 4; ++q) {
        for (int rr = wid * 8; rr < wid * 8 + 8; ++rr) {
            int n = q * 64 + rr;
            int beg = roff[n], end = roff[n + 1];
            float acc = 0.f;
            for (int e = beg; e < end; ++e)
                acc += St[sdi[e] * SP + cc];
            if (lane < SP) ASq[rr * SP + lane] = acc;
        }
        __syncthreads();

        for (int n = 0; n < 64; ++n) {
            float as = ASq[n * SP + cc];
            const float* sr = &St[(q * 64 + n) * SP];
            #pragma unroll
            for (int j = 0; j < 7; ++j) {
                int k = wid + j * 8;
                int kcl = (k < SP) ? k : (SP - 1);
                ap[j] += sr[kcl] * as;
            }
        }
        __syncthreads();
    }

    float tr = 0.f;
    #pragma unroll
    for (int j = 0; j < 7; ++j) {
        int k = wid + j * 8;
        if (k < SP && lane < SP) {
            g_Ap[(size_t)g * SP * SP + k * SP + lane] = ap[j];
            if (lane == k) tr += ap[j];
        }
    }

    float r = blockReduceN(tr, red, 8);
    if (tid == 0) atomicAdd(&ws[2], r);
}

// ---- K4: combine partials, ||G||^2, dense GIN, classifier -------------------
__launch_bounds__(256, 3)
__global__ void k4_head(const float* __restrict__ W2a, const float* __restrict__ b2a,
                        const float* __restrict__ W2b, const float* __restrict__ b2b,
                        const float* __restrict__ Wl,  const float* __restrict__ bl,
                        float* __restrict__ out, float* __restrict__ ws)
{
    __shared__ __align__(16) float xpL[KC * HD];    // 12.8 KB  xp [k][d]
    __shared__ __align__(16) float Ap[KC * KC];     // 10 KB
    __shared__ __align__(16) float h2[KC * HD];     // 12.8 KB
    __shared__ __align__(16) float tt[KC * HD];     // 12.8 KB
    __shared__ float red[4];

    const int g = blockIdx.x, tid = threadIdx.x;
    const int lane = tid & 63, wid = tid >> 6;

    for (int i = tid; i < KC * HD; i += 256) {
        float v = 0.f;
        #pragma unroll
        for (int c = 0; c < NCH; ++c)
            v += g_PTp[(size_t)(g * NCH + c) * (KC * HD) + i];
        xpL[i] = v;
    }
    float sumG2 = 0.f;
    for (int i = tid; i < KC * KC; i += 256) {
        float v = 0.f;
        #pragma unroll
        for (int c = 0; c < NCH; ++c)
            v += g_Gp[(size_t)(g * NCH + c) * (KC * KC) + i];
        sumG2 += v * v;
        Ap[i] = g_Ap[(size_t)g * KC * KC + i];
    }
    __syncthreads();

    // h2[k][d] = xp[k][d] + sum_l Ap[k][l] * xp[l][d]
    for (int k = wid; k < KC; k += 4) {
        float a = xpL[k * HD + lane];
        #pragma unroll
        for (int l = 0; l < KC; ++l)
            a += Ap[k * KC + l] * xpL[l * HD + lane];
        h2[k * HD + lane] = a;
    }
    __syncthreads();

    // t = relu(h2 @ W2a + b2a)
    {
        float wr[HD];
        #pragma unroll
        for (int d = 0; d < HD; ++d) wr[d] = W2a[d * HD + lane];
        float br = b2a[lane];
        for (int k = wid; k < KC; k += 4) {
            float a0 = br, a1 = 0.f, a2 = 0.f, a3 = 0.f;
            const float4* h4 = (const float4*)&h2[k * HD];
            #pragma unroll
            for (int i = 0; i < 16; ++i) {
                float4 v = h4[i];
                a0 += v.x * wr[4*i]; a1 += v.y * wr[4*i+1];
                a2 += v.z * wr[4*i+2]; a3 += v.w * wr[4*i+3];
            }
            tt[k * HD + lane] = fmaxf((a0 + a1) + (a2 + a3), 0.f);
        }
    }
    __syncthreads();

    // h3 = t @ W2b + b2b; fold mean over k and Wl into logits partials
    float l0 = 0.f, l1 = 0.f;
    {
        float wr[HD];
        #pragma unroll
        for (int j = 0; j < HD; ++j) wr[j] = W2b[j * HD + lane];
        float br = b2b[lane];
        float wl0 = Wl[lane * 2], wl1 = Wl[lane * 2 + 1];
        for (int k = wid; k < KC; k += 4) {
            float a0 = br, a1 = 0.f, a2 = 0.f, a3 = 0.f;
            const float4* t4 = (const float4*)&tt[k * HD];
            #pragma unroll
            for (int i = 0; i < 16; ++i) {
                float4 v = t4[i];
                a0 += v.x * wr[4*i]; a1 += v.y * wr[4*i+1];
                a2 += v.z * wr[4*i+2]; a3 += v.w * wr[4*i+3];
            }
            float a = (a0 + a1) + (a2 + a3);
            l0 += a * wl0; l1 += a * wl1;
        }
    }

    float rG2 = blockReduceN(sumG2, red, 4);
    float rl0 = blockReduceN(l0, red, 4);
    float rl1 = blockReduceN(l1, red, 4);
    if (tid == 0) {
        atomicAdd(&ws[3], rG2);
        float g0 = bl[0] + rl0 * (1.f / KC);
        float g1 = bl[1] + rl1 * (1.f / KC);
        float mm = fmaxf(g0, g1);
        float lse = mm + logf(expf(g0 - mm) + expf(g1 - mm));
        out[2 * g]     = g0 - lse;
        out[2 * g + 1] = g1 - lse;
    }
}

extern "C" void kernel_launch(void* const* d_in, const int* in_sizes, int n_in,
                              void* d_out, int out_size, void* d_ws, size_t ws_size,
                              hipStream_t stream) {
    const float* x    = (const float*)d_in[0];
    const float* W1a  = (const float*)d_in[1];
    const float* b1a  = (const float*)d_in[2];
    const float* W1b  = (const float*)d_in[3];
    const float* b1b  = (const float*)d_in[4];
    const float* Wp   = (const float*)d_in[5];
    const float* bp   = (const float*)d_in[6];
    const float* W2a  = (const float*)d_in[7];
    const float* b2a  = (const float*)d_in[8];
    const float* W2b  = (const float*)d_in[9];
    const float* b2b  = (const float*)d_in[10];
    const float* Wl   = (const float*)d_in[11];
    const float* bl   = (const float*)d_in[12];
    const int*   eidx = (const int*)d_in[13];   // [2, E] int32
    float* out = (float*)d_out;
    float* ws  = (float*)d_ws;

    zero_ws<<<1, 64, 0, stream>>>(ws);
    k1a_sort<<<NG, 512, 0, stream>>>(eidx, eidx + ETOT, x);
    k1b_a2<<<NG * 4, 512, 0, stream>>>(eidx, eidx + ETOT, ws);
    k2_mlp<<<NG * NCH, 512, 0, stream>>>(W1a, b1a, W1b, b1b, Wp, bp, ws);
    k3_as<<<NG, 512, 0, stream>>>(ws);
    k4_head<<<NG, 256, 0, stream>>>(W2a, b2a, W2b, b2b, Wl, bl, out, ws);
    finalize_k<<<1, 64, 0, stream>>>(ws, out);
}